// Round 2
// baseline (258.242 us; speedup 1.0000x reference)
//
#include <hip/hip_runtime.h>

// Fused: h = relu(X @ M + d), s0 = sum(h), where
//   M = W^T @ RW  (20x20, precomputed once per call),
//   d = b @ RW + 1 (20,)
// This is algebraically identical to relu((X@W^T + b)@RW + 1).
// Then n = #halvings of f32(s0) until <= 1; out = f32(s0) * 2^-n.
//
// Main kernel: 4 rows/thread (320 contiguous bytes), M broadcast from LDS
// (j-outer: 5x ds_read_b128 per j, shared across 4 rows -> DS pipe ~15 us,
// under the 25 us HBM floor for the 160 MB X read).

#define D 20
#define BLOCK 256
#define RPT 4  // rows per thread

// d_ws layout: [0,8) double acc; at byte 16: float Mt[400]; then float dvec[20].
// Mt[j*D + k] = M[k][j] = sum_i W[i][k] * RW[i][j]   (j-major for j-outer loop)

__global__ void setup_kernel(const float* __restrict__ W,
                             const float* __restrict__ b,
                             const float* __restrict__ RW,
                             double* __restrict__ acc,
                             float* __restrict__ Mt,
                             float* __restrict__ dvec) {
    const int tid = threadIdx.x;
    if (tid == 0) acc[0] = 0.0;
    for (int idx = tid; idx < D * D; idx += blockDim.x) {
        const int j = idx / D, k = idx % D;
        float s = 0.0f;
        for (int i = 0; i < D; ++i)
            s = fmaf(W[i * D + k], RW[i * D + j], s);
        Mt[idx] = s;  // idx == j*D + k
    }
    if (tid < D) {
        float s = 1.0f;
        for (int i = 0; i < D; ++i)
            s = fmaf(b[i], RW[i * D + tid], s);
        dvec[tid] = s;
    }
}

__global__ void __launch_bounds__(BLOCK)
fused_mlp_sum(const float* __restrict__ X,
              const float* __restrict__ Mt,
              const float* __restrict__ dvec,
              double* __restrict__ acc,
              int nrows) {
    __shared__ float sM[D * D];   // sM[j*D + k] = M[k][j]
    __shared__ float sd[D];
    __shared__ float wave_sums[BLOCK / 64];

    const int tid = threadIdx.x;
    for (int i = tid; i < D * D; i += BLOCK) sM[i] = Mt[i];
    if (tid < D) sd[tid] = dvec[tid];
    __syncthreads();

    const long long t = (long long)blockIdx.x * BLOCK + tid;
    const long long row0 = t * RPT;
    float lsum = 0.0f;

    // nrows % RPT == 0 (2,000,000), so threads are all-4-rows or nothing.
    if (row0 + RPT <= nrows) {
        const float* xp = X + row0 * D;

        float x[RPT][D];
#pragma unroll
        for (int r = 0; r < RPT; ++r) {
#pragma unroll
            for (int q = 0; q < 5; ++q) {
                float4 v = ((const float4*)(xp + r * D))[q];
                x[r][4 * q + 0] = v.x; x[r][4 * q + 1] = v.y;
                x[r][4 * q + 2] = v.z; x[r][4 * q + 3] = v.w;
            }
        }

#pragma unroll
        for (int j = 0; j < D; ++j) {
            // rv[k] = M[k][j], contiguous in sM -> 5 broadcast ds_read_b128
            float rv[D];
#pragma unroll
            for (int q = 0; q < 5; ++q) {
                float4 v = ((const float4*)(sM + j * D))[q];
                rv[4 * q + 0] = v.x; rv[4 * q + 1] = v.y;
                rv[4 * q + 2] = v.z; rv[4 * q + 3] = v.w;
            }
            float tr[RPT];
#pragma unroll
            for (int r = 0; r < RPT; ++r) tr[r] = sd[j];
#pragma unroll
            for (int k = 0; k < D; ++k) {
#pragma unroll
                for (int r = 0; r < RPT; ++r)
                    tr[r] = fmaf(x[r][k], rv[k], tr[r]);
            }
#pragma unroll
            for (int r = 0; r < RPT; ++r) lsum += fmaxf(tr[r], 0.0f);
        }
    }

    // Wave (64-lane) reduction -> block reduction -> one double atomic.
#pragma unroll
    for (int off = 32; off > 0; off >>= 1)
        lsum += __shfl_down(lsum, off, 64);
    if ((tid & 63) == 0) wave_sums[tid >> 6] = lsum;
    __syncthreads();
    if (tid == 0) {
        float bs = 0.0f;
#pragma unroll
        for (int w = 0; w < BLOCK / 64; ++w) bs += wave_sums[w];
        atomicAdd(acc, (double)bs);
    }
}

__global__ void finalize_kernel(const double* __restrict__ acc,
                                float* __restrict__ out) {
    double s0 = acc[0];
    float s = (float)s0;   // reference's s0 is f32
    int n = 0;
    while (s > 1.0f) { ++n; s *= 0.5f; }  // exact power-of-2 halvings
    out[0] = s;            // == f32(s0) * 2^-n
}

extern "C" void kernel_launch(void* const* d_in, const int* in_sizes, int n_in,
                              void* d_out, int out_size, void* d_ws, size_t ws_size,
                              hipStream_t stream) {
    const float* X  = (const float*)d_in[0];
    const float* W  = (const float*)d_in[1];
    const float* b  = (const float*)d_in[2];
    const float* RW = (const float*)d_in[3];
    float* out = (float*)d_out;

    double* acc = (double*)d_ws;
    float*  Mt  = (float*)((char*)d_ws + 16);
    float*  dv  = Mt + D * D;

    const int nrows = in_sizes[0] / D;  // 2,000,000

    setup_kernel<<<1, 256, 0, stream>>>(W, b, RW, acc, Mt, dv);

    const int nthreads = (nrows + RPT - 1) / RPT;        // 500,000
    const int blocks = (nthreads + BLOCK - 1) / BLOCK;   // 1954
    fused_mlp_sum<<<blocks, BLOCK, 0, stream>>>(X, Mt, dv, acc, nrows);
    finalize_kernel<<<1, 1, 0, stream>>>(acc, out);
}

// Round 3
// 241.079 us; speedup vs baseline: 1.0712x; 1.0712x over previous
//
#include <hip/hip_runtime.h>

// Fused: h = relu(X @ M + d), s0 = sum(h), where
//   M = W^T @ RW  (20x20, precomputed once per call),
//   d = b @ RW + 1 (20,)
// algebraically identical to relu((X@W^T + b)@RW + 1).
// Then n = #halvings of f32(s0) until <= 1; out = f32(s0) * 2^-n.
//
// Round-3 key change: M and d are read from GLOBAL at uniform (compile-time)
// indices inside the unrolled loops -> compiler emits s_load into SGPRs, and
// v_fma takes the SGPR operand directly. Per-lane registers hold only the
// 2 x-rows (40 VGPRs) -> no spill (round 2 spilled: VGPR=60 vs 105-float
// working set -> ~3 GB scratch/L2 re-reads -> 92 us L2-bound).

#define D 20
#define BLOCK 256
#define RPT 2  // rows per thread

// d_ws layout: [0,8) double acc; byte 16: float Mt[400]; then float dvec[20].
// Mt[j*D + k] = M[k][j] = sum_i W[i][k] * RW[i][j]   (j-major)

__global__ void setup_kernel(const float* __restrict__ W,
                             const float* __restrict__ b,
                             const float* __restrict__ RW,
                             double* __restrict__ acc,
                             float* __restrict__ Mt,
                             float* __restrict__ dvec) {
    const int tid = threadIdx.x;
    if (tid == 0) acc[0] = 0.0;  // d_ws is poisoned 0xAA before every launch
    for (int idx = tid; idx < D * D; idx += blockDim.x) {
        const int j = idx / D, k = idx % D;
        float s = 0.0f;
        for (int i = 0; i < D; ++i)
            s = fmaf(W[i * D + k], RW[i * D + j], s);
        Mt[idx] = s;  // idx == j*D + k
    }
    if (tid < D) {
        float s = 1.0f;
        for (int i = 0; i < D; ++i)
            s = fmaf(b[i], RW[i * D + tid], s);
        dvec[tid] = s;
    }
}

__global__ void __launch_bounds__(BLOCK)
fused_mlp_sum(const float* __restrict__ X,
              const float* __restrict__ Mt,
              const float* __restrict__ dvec,
              double* __restrict__ acc,
              int nrows) {
    __shared__ float wave_sums[BLOCK / 64];

    const int tid = threadIdx.x;
    const long long t = (long long)blockIdx.x * BLOCK + tid;
    const long long row0 = t * RPT;
    float lsum = 0.0f;

    // nrows % RPT == 0 (2,000,000), so threads are all-RPT-rows or nothing.
    if (row0 < nrows) {
        const float* xp = X + row0 * D;

        float x0[D], x1[D];
#pragma unroll
        for (int q = 0; q < 5; ++q) {
            float4 v = ((const float4*)xp)[q];
            x0[4 * q + 0] = v.x; x0[4 * q + 1] = v.y;
            x0[4 * q + 2] = v.z; x0[4 * q + 3] = v.w;
            float4 u = ((const float4*)(xp + D))[q];
            x1[4 * q + 0] = u.x; x1[4 * q + 1] = u.y;
            x1[4 * q + 2] = u.z; x1[4 * q + 3] = u.w;
        }

#pragma unroll
        for (int j = 0; j < D; ++j) {
            float t0 = dvec[j];   // uniform -> SGPR
            float t1 = t0;
#pragma unroll
            for (int k = 0; k < D; ++k) {
                const float m = Mt[j * D + k];  // uniform index -> s_load, SGPR
                t0 = fmaf(x0[k], m, t0);        // v_fma with SGPR operand
                t1 = fmaf(x1[k], m, t1);
            }
            lsum += fmaxf(t0, 0.0f) + fmaxf(t1, 0.0f);
        }
    }

    // Wave (64-lane) shuffle reduction -> block LDS -> one double atomic.
#pragma unroll
    for (int off = 32; off > 0; off >>= 1)
        lsum += __shfl_down(lsum, off, 64);
    if ((tid & 63) == 0) wave_sums[tid >> 6] = lsum;
    __syncthreads();
    if (tid == 0) {
        float bs = 0.0f;
#pragma unroll
        for (int w = 0; w < BLOCK / 64; ++w) bs += wave_sums[w];
        atomicAdd(acc, (double)bs);
    }
}

__global__ void finalize_kernel(const double* __restrict__ acc,
                                float* __restrict__ out) {
    double s0 = acc[0];
    float s = (float)s0;   // reference's s0 is f32
    int n = 0;
    while (s > 1.0f) { ++n; s *= 0.5f; }  // exact power-of-2 halvings
    out[0] = s;            // == f32(s0) * 2^-n
}

extern "C" void kernel_launch(void* const* d_in, const int* in_sizes, int n_in,
                              void* d_out, int out_size, void* d_ws, size_t ws_size,
                              hipStream_t stream) {
    const float* X  = (const float*)d_in[0];
    const float* W  = (const float*)d_in[1];
    const float* b  = (const float*)d_in[2];
    const float* RW = (const float*)d_in[3];
    float* out = (float*)d_out;

    double* acc = (double*)d_ws;
    float*  Mt  = (float*)((char*)d_ws + 16);
    float*  dv  = Mt + D * D;

    const int nrows = in_sizes[0] / D;  // 2,000,000

    setup_kernel<<<1, 256, 0, stream>>>(W, b, RW, acc, Mt, dv);

    const int nthreads = (nrows + RPT - 1) / RPT;        // 1,000,000
    const int blocks = (nthreads + BLOCK - 1) / BLOCK;   // 3907
    fused_mlp_sum<<<blocks, BLOCK, 0, stream>>>(X, Mt, dv, acc, nrows);
    finalize_kernel<<<1, 1, 0, stream>>>(acc, out);
}